// Round 1
// baseline (383.636 us; speedup 1.0000x reference)
//
#include <hip/hip_runtime.h>
#include <cstdint>

#define BB 8192
#define TT 50
#define FF 24

typedef __attribute__((ext_vector_type(8))) short short8;
typedef __attribute__((ext_vector_type(4))) float f32x4;

__device__ __forceinline__ float sigf(float x){ return 1.0f/(1.0f + __expf(-x)); }

// 2-way bf16 split (truncation): w ~= s1 + s2 to ~16 mantissa bits
__device__ __forceinline__ void split2(float w, unsigned short& s1, unsigned short& s2){
  unsigned b = __float_as_uint(w);
  s1 = (unsigned short)(b >> 16);
  float r = w - __uint_as_float(b & 0xFFFF0000u);
  s2 = (unsigned short)(__float_as_uint(r) >> 16);
}

#define MFMA(A,B,C) __builtin_amdgcn_mfma_f32_16x16x32_bf16((A),(B),(C),0,0,0)
#define PROD3(C,A1,A2,Bq1,Bq2) \
  C = MFMA(A1,Bq1,C); C = MFMA(A1,Bq2,C); C = MFMA(A2,Bq1,C);

// Round 9: latency-bound skeleton -> 2-group software pipeline.
// Each block owns TWO independent 8-row batch groups (A=rows b0..b0+7,
// B=rows b0+8..b0+15), offset by half a step. Each phase = {gates of one
// group || full MFMA stage of the other group} so the gate latency chain
// (z ds_read -> sigmoid chain -> pack -> h ds_write) overlaps the MFMA
// chain of independent rows. B-frags (register hog) shared across groups.
// MFMA tiles half-filled (8 of 16 rows) -- MfmaUtil was 24%, headroom 4x.

// ---------------- ae_A: L1 + L2 -> h2ws[B][32] ----------------
__global__ __launch_bounds__(512,4) void ae_A(
    const float* __restrict__ x,
    const float* __restrict__ W1, const float* __restrict__ U1, const float* __restrict__ b1,
    const float* __restrict__ W2, const float* __restrict__ U2, const float* __restrict__ b2,
    float* __restrict__ h2ws)
{
  constexpr int AS1 = 104, AS2 = 40, ZS1 = 260, ZS2 = 132;
  __shared__ __align__(16) unsigned short asp1[2][2][16*AS1]; // [grp][split][x(24)|h1(64)|pad]
  __shared__ __align__(16) unsigned short asp2[2][2][16*AS2]; // [grp][split][h2(32)|pad]
  __shared__ __align__(16) float zs1[2][8*ZS1];
  __shared__ __align__(16) float zs2[2][8*ZS2];

  const int tid = threadIdx.x, wave = tid>>6, lane = tid&63;
  const int quad = lane>>4, li = lane&15;
  const int b0 = blockIdx.x*16;

  short8 B1a[2][3], B1b[2][3];
#pragma unroll
  for (int nt=0; nt<2; ++nt)
#pragma unroll
  for (int ks=0; ks<3; ++ks){
    short8 v1, v2;
#pragma unroll
    for (int j=0; j<8; ++j){
      const int k = ks*32 + quad*8 + j;
      const int c = wave*32 + nt*16 + li;
      float w = (k<24) ? W1[k*256+c] : ((k<88) ? U1[(k-24)*256+c] : 0.f);
      unsigned short s1,s2; split2(w,s1,s2);
      v1[j]=(short)s1; v2[j]=(short)s2;
    }
    B1a[nt][ks]=v1; B1b[nt][ks]=v2;
  }
  short8 B2a[3], B2b[3];
#pragma unroll
  for (int ks=0; ks<3; ++ks){
    short8 v1, v2;
#pragma unroll
    for (int j=0; j<8; ++j){
      const int k = ks*32 + quad*8 + j;
      const int c = wave*16 + li;
      float w = (k<64) ? W2[k*128+c] : U2[(k-64)*128+c];
      unsigned short s1,s2; split2(w,s1,s2);
      v1[j]=(short)s1; v2[j]=(short)s2;
    }
    B2a[ks]=v1; B2b[ks]=v2;
  }
  const float bi1A = b1[wave*32+li], bi1B = b1[wave*32+16+li];
  const float bi2  = b2[wave*16+li];

  for (int i=tid; i<2*16*AS1; i+=512) ((unsigned int*)asp1)[i] = 0u;
  for (int i=tid; i<2*16*AS2; i+=512) ((unsigned int*)asp2)[i] = 0u;
  __syncthreads();
  if (tid < 8*FF){
    int r = tid/FF, f = tid - r*FF;
    unsigned short s1,s2;
    split2(x[((size_t)(b0+r)*TT + 0)*FF + f], s1,s2);
    asp1[0][0][r*AS1+f]=s1; asp1[0][1][r*AS1+f]=s2;
    split2(x[((size_t)(b0+8+r)*TT + 0)*FF + f], s1,s2);
    asp1[1][0][r*AS1+f]=s1; asp1[1][1][r*AS1+f]=s2;
  }
  float c1A[2] = {0.f,0.f}, c1B[2] = {0.f,0.f};
  float c2A = 0.f, c2B = 0.f;
  __syncthreads();

  auto mfma1 = [&](int g){
    f32x4 C0 = {bi1A,bi1A,bi1A,bi1A}, C1v = {bi1B,bi1B,bi1B,bi1B};
#pragma unroll
    for (int ks=0; ks<3; ++ks){
      const int ab = li*AS1 + ks*32 + quad*8;
      short8 A1 = *(const short8*)&asp1[g][0][ab];
      short8 A2 = *(const short8*)&asp1[g][1][ab];
      PROD3(C0,  A1,A2, B1a[0][ks],B1b[0][ks])
      PROD3(C1v, A1,A2, B1a[1][ks],B1b[1][ks])
    }
    if (quad < 2){
#pragma unroll
      for (int i2=0; i2<4; ++i2){
        zs1[g][(quad*4+i2)*ZS1 + wave*32 + li]      = C0[i2];
        zs1[g][(quad*4+i2)*ZS1 + wave*32 + 16 + li] = C1v[i2];
      }
    }
  };
  auto mfma2 = [&](int g){
    f32x4 C2 = {bi2,bi2,bi2,bi2};
#pragma unroll
    for (int ks=0; ks<2; ++ks){
      const int ab = li*AS1 + 24 + ks*32 + quad*8;
      short8 A1 = *(const short8*)&asp1[g][0][ab];
      short8 A2 = *(const short8*)&asp1[g][1][ab];
      PROD3(C2, A1,A2, B2a[ks],B2b[ks])
    }
    {
      const int ab = li*AS2 + quad*8;
      short8 A1 = *(const short8*)&asp2[g][0][ab];
      short8 A2 = *(const short8*)&asp2[g][1][ab];
      PROD3(C2, A1,A2, B2a[2],B2b[2])
    }
    if (quad < 2){
#pragma unroll
      for (int i2=0; i2<4; ++i2) zs2[g][(quad*4+i2)*ZS2 + wave*16 + li] = C2[i2];
    }
  };
  auto gate1 = [&](int g, float* c1_){
    const int row = tid>>5, c0 = 2*(tid&31);
    float2 zi = *(float2*)&zs1[g][row*ZS1 +       c0];
    float2 zf = *(float2*)&zs1[g][row*ZS1 +  64 + c0];
    float2 zg = *(float2*)&zs1[g][row*ZS1 + 128 + c0];
    float2 zo = *(float2*)&zs1[g][row*ZS1 + 192 + c0];
    float h0, h1v;
    { float ig=sigf(zi.x), fg=sigf(zf.x), gg=fmaxf(zg.x,0.f), og=sigf(zo.x);
      float cn=fg*c1_[0]+ig*gg; c1_[0]=cn; h0=og*fmaxf(cn,0.f); }
    { float ig=sigf(zi.y), fg=sigf(zf.y), gg=fmaxf(zg.y,0.f), og=sigf(zo.y);
      float cn=fg*c1_[1]+ig*gg; c1_[1]=cn; h1v=og*fmaxf(cn,0.f); }
    unsigned ba=__float_as_uint(h0), bb=__float_as_uint(h1v);
    unsigned p0 = (ba>>16) | (bb & 0xFFFF0000u);
    float ra = h0  - __uint_as_float(ba & 0xFFFF0000u);
    float rb = h1v - __uint_as_float(bb & 0xFFFF0000u);
    unsigned p1 = (__float_as_uint(ra)>>16) | (__float_as_uint(rb) & 0xFFFF0000u);
    *(unsigned*)&asp1[g][0][row*AS1 + 24 + c0] = p0;
    *(unsigned*)&asp1[g][1][row*AS1 + 24 + c0] = p1;
  };
  auto gate2 = [&](int g, float& c2_){
    const int tid2 = tid - 256;
    const int row = tid2>>5, c = tid2&31;
    float zi = zs2[g][row*ZS2 +      c];
    float zf = zs2[g][row*ZS2 + 32 + c];
    float zg = zs2[g][row*ZS2 + 64 + c];
    float zo = zs2[g][row*ZS2 + 96 + c];
    float ig=sigf(zi), fg=sigf(zf), gg=fmaxf(zg,0.f), og=sigf(zo);
    float cn=fg*c2_+ig*gg; c2_=cn; float h=og*fmaxf(cn,0.f);
    unsigned short s1,s2; split2(h,s1,s2);
    asp2[g][0][row*AS2+c]=s1; asp2[g][1][row*AS2+c]=s2;
  };
  auto gate2fin = [&](int g, float c2_){
    const int tid2 = tid - 256;
    const int row = tid2>>5, c = tid2&31;
    float zi = zs2[g][row*ZS2 +      c];
    float zf = zs2[g][row*ZS2 + 32 + c];
    float zg = zs2[g][row*ZS2 + 64 + c];
    float zo = zs2[g][row*ZS2 + 96 + c];
    float ig=sigf(zi), fg=sigf(zf), gg=fmaxf(zg,0.f), og=sigf(zo);
    float cn=fg*c2_+ig*gg; float h=og*fmaxf(cn,0.f);
    h2ws[(size_t)(b0+g*8+row)*32 + c] = h;
  };
  auto stagex = [&](int g, int tn){
    const int tid2 = tid - 256;
    if (tid2 < 8*FF){
      int r = tid2/FF, f = tid2 - r*FF;
      unsigned short s1,s2;
      split2(x[((size_t)(b0+g*8+r)*TT + tn)*FF + f], s1,s2);
      asp1[g][0][r*AS1+f]=s1; asp1[g][1][r*AS1+f]=s2;
    }
  };

  // prologue: z1(0) for both groups
  mfma1(0); mfma1(1);
  __syncthreads();

#pragma unroll 1
  for (int t=0; t<TT; ++t){
    // P1: Mfma_B { z2_B(t-1), z1_B(t) }  ||  Gate_A(t)
    if (t > 0){ mfma2(1); mfma1(1); }
    if (wave < 4) gate1(0, c1A);
    else { if (t > 0) gate2(0, c2A); if (t+1 < TT) stagex(0, t+1); }
    __syncthreads();
    // P2: Mfma_A { z2_A(t), z1_A(t+1) }  ||  Gate_B(t)
    mfma2(0);
    if (t+1 < TT) mfma1(0);
    if (wave < 4) gate1(1, c1B);
    else { if (t > 0) gate2(1, c2B); if (t+1 < TT) stagex(1, t+1); }
    __syncthreads();
  }
  // epilogue: z2_B(TT-1) while gate2_A(TT-1) finishes; then gate2_B(TT-1)
  mfma2(1);
  if (wave >= 4) gate2fin(0, c2A);
  __syncthreads();
  if (wave >= 4) gate2fin(1, c2B);
}

// ---------------- ae_C: L3 + fused dense -> out[B][T][24] ----------------
__global__ __launch_bounds__(512,4) void ae_C(
    const float* __restrict__ h2ws,
    const float* __restrict__ W3, const float* __restrict__ U3, const float* __restrict__ b3,
    const float* __restrict__ Wd, const float* __restrict__ bd,
    float* __restrict__ out)
{
  constexpr int AS2 = 40, AS3 = 72, ZS1 = 260;
  __shared__ __align__(16) unsigned short asp2[2][2][16*AS2]; // [grp][split][h2(32)|pad]
  __shared__ __align__(16) unsigned short asp3[2][2][16*AS3]; // [grp][split][h3(64)|pad]
  __shared__ __align__(16) float zs1[2][8*ZS1];

  const int tid = threadIdx.x, wave = tid>>6, lane = tid&63;
  const int quad = lane>>4, li = lane&15;
  const int b0 = blockIdx.x*16;

  // U3 B-frags
  short8 B3a[2][2], B3b[2][2];
#pragma unroll
  for (int nt=0; nt<2; ++nt)
#pragma unroll
  for (int ks=0; ks<2; ++ks){
    short8 v1, v2;
#pragma unroll
    for (int j=0; j<8; ++j){
      const int k = ks*32 + quad*8 + j;
      const int c = wave*32 + nt*16 + li;
      float w = U3[k*256+c];
      unsigned short s1,s2; split2(w,s1,s2);
      v1[j]=(short)s1; v2[j]=(short)s2;
    }
    B3a[nt][ks]=v1; B3b[nt][ks]=v2;
  }
  // W3 B-frags (K=32, one kstep)
  short8 W3a[2], W3b[2];
#pragma unroll
  for (int nt=0; nt<2; ++nt){
    short8 v1, v2;
#pragma unroll
    for (int j=0; j<8; ++j){
      const int k = quad*8 + j;
      const int c = wave*32 + nt*16 + li;
      float w = W3[k*256+c];
      unsigned short s1,s2; split2(w,s1,s2);
      v1[j]=(short)s1; v2[j]=(short)s2;
    }
    W3a[nt]=v1; W3b[nt]=v2;
  }
  // dense B-frags on waves 0/1
  short8 Bda[2], Bdb[2];
  const int dcol = wave*16 + li;
  const bool dW = (wave < 2), dOK = dW && (dcol < 24);
  const float bdv = dOK ? bd[dcol] : 0.f;
#pragma unroll
  for (int ks=0; ks<2; ++ks){
    short8 v1, v2;
#pragma unroll
    for (int j=0; j<8; ++j){
      const int k = ks*32 + quad*8 + j;
      float w = dOK ? Wd[k*24+dcol] : 0.f;
      unsigned short s1,s2; split2(w,s1,s2);
      v1[j]=(short)s1; v2[j]=(short)s2;
    }
    Bda[ks]=v1; Bdb[ks]=v2;
  }
  const float bi3A = b3[wave*32+li], bi3B = b3[wave*32+16+li];

  for (int i=tid; i<2*16*AS2; i+=512) ((unsigned int*)asp2)[i] = 0u;
  for (int i=tid; i<2*16*AS3; i+=512) ((unsigned int*)asp3)[i] = 0u;
  __syncthreads();

  // stage h2 splits, both groups (rows 0..7 each)
  if (tid < 256){
    const int row = tid>>5, ch = tid&31;
    unsigned short s1,s2;
    split2(h2ws[(size_t)(b0+row)*32 + ch], s1,s2);
    asp2[0][0][row*AS2+ch]=s1; asp2[0][1][row*AS2+ch]=s2;
    split2(h2ws[(size_t)(b0+8+row)*32 + ch], s1,s2);
    asp2[1][0][row*AS2+ch]=s1; asp2[1][1][row*AS2+ch]=s2;
  }
  __syncthreads();

  // ZR = b3 + h2 @ W3 for both groups (kept in regs as C-init; staged to zs1)
  float zr0A[4], zr1A[4], zr0B[4], zr1B[4];
  auto zrcalc = [&](int g, float* zr0, float* zr1){
    f32x4 Z0 = {bi3A,bi3A,bi3A,bi3A}, Z1 = {bi3B,bi3B,bi3B,bi3B};
    const int ab = li*AS2 + quad*8;
    short8 A1 = *(const short8*)&asp2[g][0][ab];
    short8 A2 = *(const short8*)&asp2[g][1][ab];
    PROD3(Z0, A1,A2, W3a[0],W3b[0])
    PROD3(Z1, A1,A2, W3a[1],W3b[1])
#pragma unroll
    for (int i2=0; i2<4; ++i2){
      zr0[i2]=Z0[i2]; zr1[i2]=Z1[i2];
      if (quad < 2){
        zs1[g][(quad*4+i2)*ZS1 + wave*32 + li]      = Z0[i2];
        zs1[g][(quad*4+i2)*ZS1 + wave*32 + 16 + li] = Z1[i2];
      }
    }
  };
  zrcalc(0, zr0A, zr1A); zrcalc(1, zr0B, zr1B);
  float c3A = 0.f, c3B = 0.f;
  __syncthreads();

  auto gate3 = [&](int g, float& c3_){
    const int row = tid>>6, c = tid&63;   // row == wave
    float zi = zs1[g][row*ZS1 +       c];
    float zf = zs1[g][row*ZS1 +  64 + c];
    float zg = zs1[g][row*ZS1 + 128 + c];
    float zo = zs1[g][row*ZS1 + 192 + c];
    float ig=sigf(zi), fg=sigf(zf), gg=fmaxf(zg,0.f), og=sigf(zo);
    float cn=fg*c3_+ig*gg; c3_=cn; float h=og*fmaxf(cn,0.f);
    unsigned short s1,s2; split2(h,s1,s2);
    asp3[g][0][row*AS3+c]=s1; asp3[g][1][row*AS3+c]=s2;
  };
  auto mfmaC = [&](int g, const float* zr0, const float* zr1, int t){
    f32x4 C0  = {zr0[0],zr0[1],zr0[2],zr0[3]};
    f32x4 C1v = {zr1[0],zr1[1],zr1[2],zr1[3]};
    f32x4 Cd  = {bdv,bdv,bdv,bdv};
#pragma unroll
    for (int ks=0; ks<2; ++ks){
      const int ab = li*AS3 + ks*32 + quad*8;
      short8 A1 = *(const short8*)&asp3[g][0][ab];
      short8 A2 = *(const short8*)&asp3[g][1][ab];
      PROD3(C0,  A1,A2, B3a[0][ks],B3b[0][ks])
      PROD3(C1v, A1,A2, B3a[1][ks],B3b[1][ks])
      if (dW){ PROD3(Cd, A1,A2, Bda[ks],Bdb[ks]) }
    }
    if (quad < 2){
#pragma unroll
      for (int i2=0; i2<4; ++i2){
        zs1[g][(quad*4+i2)*ZS1 + wave*32 + li]      = C0[i2];
        zs1[g][(quad*4+i2)*ZS1 + wave*32 + 16 + li] = C1v[i2];
      }
    }
    if (dOK && quad < 2){
#pragma unroll
      for (int i2=0; i2<4; ++i2)
        out[((size_t)(b0+g*8+quad*4+i2)*TT + (t-1))*FF + dcol] = Cd[i2];
    }
  };
  auto denseOnly = [&](int g, int t){
    if (!dW) return;
    f32x4 Cd = {bdv,bdv,bdv,bdv};
#pragma unroll
    for (int ks=0; ks<2; ++ks){
      const int ab = li*AS3 + ks*32 + quad*8;
      short8 A1 = *(const short8*)&asp3[g][0][ab];
      short8 A2 = *(const short8*)&asp3[g][1][ab];
      PROD3(Cd, A1,A2, Bda[ks],Bdb[ks])
    }
    if (dOK && quad < 2){
#pragma unroll
      for (int i2=0; i2<4; ++i2)
        out[((size_t)(b0+g*8+quad*4+i2)*TT + t)*FF + dcol] = Cd[i2];
    }
  };

#pragma unroll 1
  for (int t=0; t<TT; ++t){
    // P1: Mfma_B(t) { z3_B(t) + dense_B(t-1) }  ||  Gate_A(t)
    if (t > 0) mfmaC(1, zr0B, zr1B, t);
    gate3(0, c3A);
    __syncthreads();
    // P2: Mfma_A(t+1) (or final dense_A)  ||  Gate_B(t)
    if (t+1 < TT) mfmaC(0, zr0A, zr1A, t+1);
    else          denseOnly(0, TT-1);
    gate3(1, c3B);
    __syncthreads();
  }
  denseOnly(1, TT-1);
}

extern "C" void kernel_launch(void* const* d_in, const int* in_sizes, int n_in,
                              void* d_out, int out_size, void* d_ws, size_t ws_size,
                              hipStream_t stream){
  const float* x  = (const float*)d_in[0];
  const float* W1 = (const float*)d_in[1];
  const float* U1 = (const float*)d_in[2];
  const float* b1 = (const float*)d_in[3];
  const float* W2 = (const float*)d_in[4];
  const float* U2 = (const float*)d_in[5];
  const float* b2 = (const float*)d_in[6];
  const float* W3 = (const float*)d_in[7];
  const float* U3 = (const float*)d_in[8];
  const float* b3 = (const float*)d_in[9];
  const float* Wd = (const float*)d_in[10];
  const float* bd = (const float*)d_in[11];
  float* out = (float*)d_out;
  float* h2ws = (float*)d_ws;                  // [B][32] = 1 MB

  hipLaunchKernelGGL(ae_A, dim3(512), dim3(512), 0, stream,
                     x, W1, U1, b1, W2, U2, b2, h2ws);
  hipLaunchKernelGGL(ae_C, dim3(512), dim3(512), 0, stream,
                     h2ws, W3, U3, b3, Wd, bd, out);
}

// Round 2
// 289.338 us; speedup vs baseline: 1.3259x; 1.3259x over previous
//
#include <hip/hip_runtime.h>
#include <cstdint>

#define BB 8192
#define TT 50
#define FF 24
#define ROWS 32

typedef __attribute__((ext_vector_type(8))) short short8;
typedef __attribute__((ext_vector_type(4))) float f32x4;

__device__ __forceinline__ float sigf(float x){ return 1.0f/(1.0f + __expf(-x)); }

// 2-way bf16 split (truncation): w ~= s1 + s2 to ~16 mantissa bits
__device__ __forceinline__ void split2(float w, unsigned short& s1, unsigned short& s2){
  unsigned b = __float_as_uint(w);
  s1 = (unsigned short)(b >> 16);
  float r = w - __uint_as_float(b & 0xFFFF0000u);
  s2 = (unsigned short)(__float_as_uint(r) >> 16);
}

#define MFMA(A,B,C) __builtin_amdgcn_mfma_f32_16x16x32_bf16((A),(B),(C),0,0,0)

// Round 10: TRANSPOSED-MFMA formulation. z^T = Wt * act^T: weights are the
// A (m) operand, activations the B (n) operand. M-rows of each 16-wide tile
// are permuted so lane (quad,li) reg i2 holds gate i2 (i,f,g,o) of hidden
// (4*wave+quad) for batch row li -- gates are pure per-lane VALU on the
// accumulator: NO z LDS round-trip, NO cross-lane ops, ONE barrier/step.
// 32 rows/block, 256 blocks (1 block/CU), 16 waves. MFMA count unchanged
// vs round-8. Act B-frag reads identical to round-8's proven A-frag reads.
// verified maps (m89): A[m=lane&15][k=quad*8+j], B[k=quad*8+j][n=lane&15],
// C: col(n)=lane&15, row(m)=quad*4+reg.

// ---------------- ae_A: L1 + L2 -> h2ws[B][32] ----------------
// Phase t (t=0..TT): all waves: z1(t)=x(t)W1+h1(t-1)U1 via MFMA (tile=wave),
// gates -> h1(t) -> a1[ns]. Waves 0-7: z2(t-1)=h1(t-1)W2+h2(t-2)U2, gates ->
// h2(t-1) -> a2[ns] (t==TT: -> h2ws). Waves 8-15: stage x(t+1) (depth-2
// register prefetch). One __syncthreads per phase.
__global__ __launch_bounds__(1024,4) void ae_A(
    const float* __restrict__ x,
    const float* __restrict__ W1, const float* __restrict__ U1, const float* __restrict__ b1,
    const float* __restrict__ W2, const float* __restrict__ U2, const float* __restrict__ b2,
    float* __restrict__ h2ws)
{
  constexpr int AS1 = 104, AS2 = 32;
  __shared__ __align__(16) unsigned short a1[2][2][ROWS*AS1]; // [slot][split][row*AS1 + (x24|h1 64|pad)]
  __shared__ __align__(16) unsigned short a2[2][2][ROWS*AS2]; // [slot][split][row*AS2 + h2]

  const int tid = threadIdx.x, wave = tid>>6, lane = tid&63;
  const int quad = lane>>4, li = lane&15;
  const int b0 = blockIdx.x*ROWS;

  // L1 weight A-frags: tile = wave (16 tiles cover 256 zcols).
  // zcol(m) = (m&3)*64 + 4*wave + (m>>2); A[m=li][k=ks*32+quad*8+j]
  short8 A1w[3], A2w[3];
  {
    const int zc = (li&3)*64 + 4*wave + (li>>2);
#pragma unroll
    for (int ks=0; ks<3; ++ks){
      short8 v1, v2;
#pragma unroll
      for (int j=0; j<8; ++j){
        const int k = ks*32 + quad*8 + j;
        float w = (k<24) ? W1[k*256+zc] : ((k<88) ? U1[(k-24)*256+zc] : 0.f);
        unsigned short s1,s2; split2(w,s1,s2);
        v1[j]=(short)s1; v2[j]=(short)s2;
      }
      A1w[ks]=v1; A2w[ks]=v2;
    }
  }
  f32x4 bi1;
#pragma unroll
  for (int i2=0;i2<4;++i2) bi1[i2] = b1[i2*64 + 4*wave + quad];

  // L2 weight A-frags on waves 0-7 (8 tiles cover 128 zcols).
  const bool hasL2 = (wave < 8);
  short8 A1w2[3], A2w2[3];
  f32x4 bi2;
  if (hasL2){
    const int zc = (li&3)*32 + 4*wave + (li>>2);
#pragma unroll
    for (int ks=0; ks<3; ++ks){
      short8 v1, v2;
#pragma unroll
      for (int j=0; j<8; ++j){
        const int k = ks*32 + quad*8 + j;
        float w = (k<64) ? W2[k*128+zc] : U2[(k-64)*128+zc];
        unsigned short s1,s2; split2(w,s1,s2);
        v1[j]=(short)s1; v2[j]=(short)s2;
      }
      A1w2[ks]=v1; A2w2[ks]=v2;
    }
#pragma unroll
    for (int i2=0;i2<4;++i2) bi2[i2] = b2[i2*32 + 4*wave + quad];
  }

  // zero LDS (both slots: h regions must read as 0 at t=0, pad always 0)
  { unsigned* p1 = (unsigned*)a1; for (int i=tid;i<2*2*ROWS*AS1/2;i+=1024) p1[i]=0u;
    unsigned* p2 = (unsigned*)a2; for (int i=tid;i<2*2*ROWS*AS2/2;i+=1024) p2[i]=0u; }
  __syncthreads();
  // stage x(0) into slot 0
  if (tid < ROWS*FF){
    const int r = tid/FF, f = tid - r*FF;
    unsigned short s1,s2; split2(x[((size_t)(b0+r)*TT + 0)*FF + f], s1,s2);
    a1[0][0][r*AS1+f]=s1; a1[0][1][r*AS1+f]=s2;
  }
  // x prefetch state (waves 8-15): depth-2 register pipeline
  const int tid2 = tid - 512;
  int pr0=0, pf0=0, pr1=0, pf1=0; bool pe1=false;
  const float *xp0=nullptr, *xp1=nullptr;
  float va0=0.f, va1=0.f, vb0=0.f, vb1=0.f;
  if (wave >= 8){
    pr0 = tid2/FF; pf0 = tid2 - pr0*FF;
    xp0 = x + (size_t)(b0+pr0)*TT*FF + pf0;
    pe1 = (tid2+512) < ROWS*FF;
    if (pe1){ pr1 = (tid2+512)/FF; pf1 = (tid2+512) - pr1*FF;
              xp1 = x + (size_t)(b0+pr1)*TT*FF + pf1; }
    va0 = xp0[1*FF]; if (pe1) va1 = xp1[1*FF];   // x(1)
    vb0 = xp0[2*FF]; if (pe1) vb1 = xp1[2*FF];   // x(2)
  }
  float c1s[2] = {0.f,0.f};
  float c2s[2] = {0.f,0.f};
  __syncthreads();

#pragma unroll 1
  for (int t=0; t<=TT; ++t){
    const int s = t&1, ns = s^1;
    // ---- L1: z1(t) + gates -> h1(t) (all 16 waves) ----
    if (t < TT){
#pragma unroll
      for (int rg=0; rg<2; ++rg){
        f32x4 C = bi1;
#pragma unroll
        for (int ks=0; ks<3; ++ks){
          const int ab = (rg*16+li)*AS1 + ks*32 + quad*8;
          short8 Ba = *(const short8*)&a1[s][0][ab];
          short8 Bb = *(const short8*)&a1[s][1][ab];
          C = MFMA(A1w[ks], Ba, C);   // w_hi * a_hi
          C = MFMA(A1w[ks], Bb, C);   // w_hi * a_lo
          C = MFMA(A2w[ks], Ba, C);   // w_lo * a_hi
        }
        const float ig = sigf(C[0]), fg = sigf(C[1]);
        const float gg = fmaxf(C[2],0.f), og = sigf(C[3]);
        const float cn = fg*c1s[rg] + ig*gg; c1s[rg] = cn;
        const float h = og*fmaxf(cn,0.f);
        unsigned short s1,s2; split2(h,s1,s2);
        const int hw = (rg*16+li)*AS1 + 24 + 4*wave + quad;
        a1[ns][0][hw] = s1; a1[ns][1][hw] = s2;
      }
    }
    // ---- L2: z2(t-1) + gates -> h2(t-1) (waves 0-7) ----
    if (hasL2 && t >= 1){
#pragma unroll
      for (int rg=0; rg<2; ++rg){
        f32x4 C = bi2;
#pragma unroll
        for (int ks=0; ks<2; ++ks){
          const int ab = (rg*16+li)*AS1 + 24 + ks*32 + quad*8;
          short8 Ba = *(const short8*)&a1[s][0][ab];
          short8 Bb = *(const short8*)&a1[s][1][ab];
          C = MFMA(A1w2[ks], Ba, C);
          C = MFMA(A1w2[ks], Bb, C);
          C = MFMA(A2w2[ks], Ba, C);
        }
        {
          const int ab = (rg*16+li)*AS2 + quad*8;
          short8 Ba = *(const short8*)&a2[s][0][ab];
          short8 Bb = *(const short8*)&a2[s][1][ab];
          C = MFMA(A1w2[2], Ba, C);
          C = MFMA(A1w2[2], Bb, C);
          C = MFMA(A2w2[2], Ba, C);
        }
        const float ig = sigf(C[0]), fg = sigf(C[1]);
        const float gg = fmaxf(C[2],0.f), og = sigf(C[3]);
        const float cn = fg*c2s[rg] + ig*gg; c2s[rg] = cn;
        const float h = og*fmaxf(cn,0.f);
        if (t < TT){
          unsigned short s1,s2; split2(h,s1,s2);
          const int hw = (rg*16+li)*AS2 + 4*wave + quad;
          a2[ns][0][hw] = s1; a2[ns][1][hw] = s2;
        } else {
          h2ws[(size_t)(b0+rg*16+li)*32 + 4*wave + quad] = h;  // final h2(TT-1)
        }
      }
    }
    // ---- x staging (waves 8-15): write x(t+1), prefetch x(t+3) ----
    if (wave >= 8 && t < TT-1){
      unsigned short s1,s2;
      split2(va0,s1,s2); a1[ns][0][pr0*AS1+pf0]=s1; a1[ns][1][pr0*AS1+pf0]=s2;
      if (pe1){ split2(va1,s1,s2); a1[ns][0][pr1*AS1+pf1]=s1; a1[ns][1][pr1*AS1+pf1]=s2; }
      va0 = vb0; va1 = vb1;
      if (t+3 < TT){ vb0 = xp0[(t+3)*FF]; if (pe1) vb1 = xp1[(t+3)*FF]; }
    }
    __syncthreads();
  }
}

// ---------------- ae_C: L3 + fused dense -> out[B][T][24] ----------------
// Same transposed scheme: L3 tile = wave (16 tiles / 256 zcols), ZR = b3 +
// h2@W3 held in regs as per-phase C-init. Dense (normal orientation) rides
// on waves 0-3, reusing the same activation fragments.
__global__ __launch_bounds__(1024,4) void ae_C(
    const float* __restrict__ h2ws,
    const float* __restrict__ W3, const float* __restrict__ U3, const float* __restrict__ b3,
    const float* __restrict__ Wd, const float* __restrict__ bd,
    float* __restrict__ out)
{
  constexpr int AS3 = 72;
  __shared__ __align__(16) unsigned short a3[2][2][ROWS*AS3];  // [slot][split][row*AS3 + h3(64)|pad]
  __shared__ __align__(16) unsigned short a2h[2][ROWS*32];     // h2 splits (static)

  const int tid = threadIdx.x, wave = tid>>6, lane = tid&63;
  const int quad = lane>>4, li = lane&15;
  const int b0 = blockIdx.x*ROWS;

  const int zc3 = (li&3)*64 + 4*wave + (li>>2);
  // U3 A-frags (K=64, 2 ksteps)
  short8 A1u[2], A2u[2];
#pragma unroll
  for (int ks=0; ks<2; ++ks){
    short8 v1, v2;
#pragma unroll
    for (int j=0; j<8; ++j){
      const int k = ks*32 + quad*8 + j;
      float w = U3[k*256+zc3];
      unsigned short s1,s2; split2(w,s1,s2);
      v1[j]=(short)s1; v2[j]=(short)s2;
    }
    A1u[ks]=v1; A2u[ks]=v2;
  }
  // W3 A-frags (K=32, 1 kstep) -- prologue only
  short8 A1w3, A2w3;
  {
    short8 v1, v2;
#pragma unroll
    for (int j=0; j<8; ++j){
      const int k = quad*8 + j;
      float w = W3[k*256+zc3];
      unsigned short s1,s2; split2(w,s1,s2);
      v1[j]=(short)s1; v2[j]=(short)s2;
    }
    A1w3=v1; A2w3=v2;
  }
  f32x4 bi3;
#pragma unroll
  for (int i2=0;i2<4;++i2) bi3[i2] = b3[i2*64 + 4*wave + quad];

  // dense B-frags on waves 0-3: wave0: rg0 cols0-15, wave1: rg0 cols16-23,
  // wave2: rg1 cols0-15, wave3: rg1 cols16-23 (one wave per SIMD).
  const bool dW = (wave < 4);
  const int myrg = (wave>>1)&1;
  const int dcol = (wave&1)*16 + li;
  const bool dOK = dW && (dcol < 24);
  const float bdv = dOK ? bd[dcol] : 0.f;
  short8 Bd1[2], Bd2[2];
  if (dW){
#pragma unroll
    for (int ks=0; ks<2; ++ks){
      short8 v1, v2;
#pragma unroll
      for (int j=0; j<8; ++j){
        const int k = ks*32 + quad*8 + j;
        float w = dOK ? Wd[k*24+dcol] : 0.f;
        unsigned short s1,s2; split2(w,s1,s2);
        v1[j]=(short)s1; v2[j]=(short)s2;
      }
      Bd1[ks]=v1; Bd2[ks]=v2;
    }
  }

  // zero a3 (both slots), stage h2 splits
  { unsigned* p = (unsigned*)a3; for (int i=tid;i<2*2*ROWS*AS3/2;i+=1024) p[i]=0u; }
  {
    const int r = tid>>5, ch = tid&31;
    unsigned short s1,s2; split2(h2ws[(size_t)(b0+r)*32 + ch], s1,s2);
    a2h[0][r*32+ch]=s1; a2h[1][r*32+ch]=s2;
  }
  __syncthreads();

  // ZR = b3 + h2@W3 (per-lane, kept as C-init for every phase)
  f32x4 zr[2];
#pragma unroll
  for (int rg=0; rg<2; ++rg){
    f32x4 C = bi3;
    const int ab = (rg*16+li)*32 + quad*8;
    short8 Ba = *(const short8*)&a2h[0][ab];
    short8 Bb = *(const short8*)&a2h[1][ab];
    C = MFMA(A1w3, Ba, C);
    C = MFMA(A1w3, Bb, C);
    C = MFMA(A2w3, Ba, C);
    zr[rg] = C;
  }
  float c3s[2] = {0.f,0.f};

#pragma unroll 1
  for (int t=0; t<=TT; ++t){
    const int s = t&1, ns = s^1;
    if (t < TT){
#pragma unroll
      for (int rg=0; rg<2; ++rg){
        f32x4 C = zr[rg];
        f32x4 Cd = {bdv,bdv,bdv,bdv};
        const bool doD = dW && (rg==myrg) && (t>0);
#pragma unroll
        for (int ks=0; ks<2; ++ks){
          const int ab = (rg*16+li)*AS3 + ks*32 + quad*8;
          short8 Ba = *(const short8*)&a3[s][0][ab];
          short8 Bb = *(const short8*)&a3[s][1][ab];
          C = MFMA(A1u[ks], Ba, C);
          C = MFMA(A1u[ks], Bb, C);
          C = MFMA(A2u[ks], Ba, C);
          if (doD){
            Cd = MFMA(Ba, Bd1[ks], Cd);  // a_hi * w_hi (normal orientation)
            Cd = MFMA(Ba, Bd2[ks], Cd);  // a_hi * w_lo
            Cd = MFMA(Bb, Bd1[ks], Cd);  // a_lo * w_hi
          }
        }
        const float ig = sigf(C[0]), fg = sigf(C[1]);
        const float gg = fmaxf(C[2],0.f), og = sigf(C[3]);
        const float cn = fg*c3s[rg] + ig*gg; c3s[rg] = cn;
        const float h = og*fmaxf(cn,0.f);
        unsigned short s1,s2; split2(h,s1,s2);
        const int hw = (rg*16+li)*AS3 + 4*wave + quad;
        a3[ns][0][hw]=s1; a3[ns][1][hw]=s2;
        if (doD && dcol < 24){
#pragma unroll
          for (int i2=0;i2<4;++i2)
            out[((size_t)(b0+myrg*16+quad*4+i2)*TT + (t-1))*FF + dcol] = Cd[i2];
        }
      }
    } else {
      // t == TT: final dense on h3(TT-1)
      if (dW){
        f32x4 Cd = {bdv,bdv,bdv,bdv};
#pragma unroll
        for (int ks=0; ks<2; ++ks){
          const int ab = (myrg*16+li)*AS3 + ks*32 + quad*8;
          short8 Ba = *(const short8*)&a3[s][0][ab];
          short8 Bb = *(const short8*)&a3[s][1][ab];
          Cd = MFMA(Ba, Bd1[ks], Cd);
          Cd = MFMA(Ba, Bd2[ks], Cd);
          Cd = MFMA(Bb, Bd1[ks], Cd);
        }
        if (dcol < 24){
#pragma unroll
          for (int i2=0;i2<4;++i2)
            out[((size_t)(b0+myrg*16+quad*4+i2)*TT + (TT-1))*FF + dcol] = Cd[i2];
        }
      }
    }
    __syncthreads();
  }
}

extern "C" void kernel_launch(void* const* d_in, const int* in_sizes, int n_in,
                              void* d_out, int out_size, void* d_ws, size_t ws_size,
                              hipStream_t stream){
  const float* x  = (const float*)d_in[0];
  const float* W1 = (const float*)d_in[1];
  const float* U1 = (const float*)d_in[2];
  const float* b1 = (const float*)d_in[3];
  const float* W2 = (const float*)d_in[4];
  const float* U2 = (const float*)d_in[5];
  const float* b2 = (const float*)d_in[6];
  const float* W3 = (const float*)d_in[7];
  const float* U3 = (const float*)d_in[8];
  const float* b3 = (const float*)d_in[9];
  const float* Wd = (const float*)d_in[10];
  const float* bd = (const float*)d_in[11];
  float* out = (float*)d_out;
  float* h2ws = (float*)d_ws;                  // [B][32] = 1 MB

  hipLaunchKernelGGL(ae_A, dim3(BB/ROWS), dim3(1024), 0, stream,
                     x, W1, U1, b1, W2, U2, b2, h2ws);
  hipLaunchKernelGGL(ae_C, dim3(BB/ROWS), dim3(1024), 0, stream,
                     h2ws, W3, U3, b3, Wd, bd, out);
}

// Round 3
// 281.465 us; speedup vs baseline: 1.3630x; 1.0280x over previous
//
#include <hip/hip_runtime.h>
#include <cstdint>

#define BB 8192
#define TT 50
#define FF 24
#define ROWS 32

typedef __attribute__((ext_vector_type(8))) short short8;
typedef __attribute__((ext_vector_type(4))) float f32x4;

__device__ __forceinline__ float sigf(float x){ return 1.0f/(1.0f + __expf(-x)); }

// 2-way bf16 split (truncation): w ~= s1 + s2 to ~16 mantissa bits
__device__ __forceinline__ void split2(float w, unsigned short& s1, unsigned short& s2){
  unsigned b = __float_as_uint(w);
  s1 = (unsigned short)(b >> 16);
  float r = w - __uint_as_float(b & 0xFFFF0000u);
  s2 = (unsigned short)(__float_as_uint(r) >> 16);
}

#define MFMA(A,B,C) __builtin_amdgcn_mfma_f32_16x16x32_bf16((A),(B),(C),0,0,0)

// Round 11: keep round-10's transposed-MFMA 1-barrier skeleton; cut LDS
// read volume + fix the AS2 conflict bug.
//  - Each wave owns ONE row-group (rg = wave>>3) and TWO zcol tiles:
//    B-frag (activations) read ONCE per wave, reused for 2 A-tiles.
//    L1 reads: 192 -> 96 b128/phase. L2's 16 tile-instances spread over
//    all 16 waves (was 2rg x 8 waves): balanced 27 MFMA/wave.
//  - AS2/a2h stride 32 -> 40 shorts (80B = 5x16B, gcd(5,8)=1): the 32-short
//    stride made bank-quad = (4*li+quad)%8 -> ~8-way conflicts on every
//    a2 read (SQ_LDS_BANK_CONFLICT 2.2e7). AS1=104 (13x16B) already ok.
// zcol map per 16-wide tile tl: zc = (li&3)*<4H/4> + 4*tl + (li>>2), so
// lane (quad,li) reg i2 = gate i2 of hidden 4*tl+quad for batch row li.

// ---------------- ae_A: L1 + L2 -> h2ws[B][32] ----------------
__global__ __launch_bounds__(1024,4) void ae_A(
    const float* __restrict__ x,
    const float* __restrict__ W1, const float* __restrict__ U1, const float* __restrict__ b1,
    const float* __restrict__ W2, const float* __restrict__ U2, const float* __restrict__ b2,
    float* __restrict__ h2ws)
{
  constexpr int AS1 = 104, AS2 = 40;
  __shared__ __align__(16) unsigned short a1[2][2][ROWS*AS1]; // [slot][split][row*AS1 + (x24|h1 64|pad)]
  __shared__ __align__(16) unsigned short a2[2][2][ROWS*AS2]; // [slot][split][row*AS2 + h2(32)|pad]

  const int tid = threadIdx.x, wave = tid>>6, lane = tid&63;
  const int quad = lane>>4, li = lane&15;
  const int w7 = wave&7, rg = wave>>3;
  const int b0 = blockIdx.x*ROWS;
  const int arow = rg*16 + li;           // batch row this wave touches

  // L1 weight A-frags: tiles tl = 2*w7+tp (16 tiles cover 256 zcols)
  short8 A1w[2][3], A2w[2][3];
  f32x4 bi1[2];
#pragma unroll
  for (int tp=0; tp<2; ++tp){
    const int tl = 2*w7 + tp;
    const int zc = (li&3)*64 + 4*tl + (li>>2);
#pragma unroll
    for (int ks=0; ks<3; ++ks){
      short8 v1, v2;
#pragma unroll
      for (int j=0; j<8; ++j){
        const int k = ks*32 + quad*8 + j;
        float w = (k<24) ? W1[k*256+zc] : ((k<88) ? U1[(k-24)*256+zc] : 0.f);
        unsigned short s1,s2; split2(w,s1,s2);
        v1[j]=(short)s1; v2[j]=(short)s2;
      }
      A1w[tp][ks]=v1; A2w[tp][ks]=v2;
    }
#pragma unroll
    for (int i2=0;i2<4;++i2) bi1[tp][i2] = b1[i2*64 + 4*tl + quad];
  }
  // L2 weight A-frags: instance (rg, tile w7); 16 instances over 16 waves
  short8 A1w2[3], A2w2[3];
  f32x4 bi2;
  {
    const int zc = (li&3)*32 + 4*w7 + (li>>2);
#pragma unroll
    for (int ks=0; ks<3; ++ks){
      short8 v1, v2;
#pragma unroll
      for (int j=0; j<8; ++j){
        const int k = ks*32 + quad*8 + j;
        float w = (k<64) ? W2[k*128+zc] : U2[(k-64)*128+zc];
        unsigned short s1,s2; split2(w,s1,s2);
        v1[j]=(short)s1; v2[j]=(short)s2;
      }
      A1w2[ks]=v1; A2w2[ks]=v2;
    }
#pragma unroll
    for (int i2=0;i2<4;++i2) bi2[i2] = b2[i2*32 + 4*w7 + quad];
  }

  // zero LDS (h regions must read 0 at t=0; pads must stay 0 forever)
  { unsigned* p1 = (unsigned*)a1; for (int i=tid;i<2*2*ROWS*AS1/2;i+=1024) p1[i]=0u;
    unsigned* p2 = (unsigned*)a2; for (int i=tid;i<2*2*ROWS*AS2/2;i+=1024) p2[i]=0u; }
  __syncthreads();
  // stage x(0) into slot 0
  if (tid < ROWS*FF){
    const int r = tid/FF, f = tid - r*FF;
    unsigned short s1,s2; split2(x[((size_t)(b0+r)*TT + 0)*FF + f], s1,s2);
    a1[0][0][r*AS1+f]=s1; a1[0][1][r*AS1+f]=s2;
  }
  // x prefetch (all threads tid<768): depth-2 register pipeline
  int pr=0, pf=0; const float* xp=nullptr;
  float va=0.f, vb=0.f;
  const bool st = (tid < ROWS*FF);
  if (st){
    pr = tid/FF; pf = tid - pr*FF;
    xp = x + (size_t)(b0+pr)*TT*FF + pf;
    va = xp[1*FF];   // x(1)
    vb = xp[2*FF];   // x(2)
  }
  float c1s[2] = {0.f,0.f};
  float c2s = 0.f;
  const int rb1 = arow*AS1;
  const int rb2 = arow*AS2;
  const int hw1 = rb1 + 24 + 8*w7 + quad;   // +4*tp for tile tp
  const int hw2 = rb2 + 4*w7 + quad;
  __syncthreads();

#pragma unroll 1
  for (int t=0; t<=TT; ++t){
    const int s = t&1, ns = s^1;
    // ---- L1: z1(t) + gates -> h1(t) (all waves; B-frag read once) ----
    if (t < TT){
      short8 Ba[3], Bb[3];
#pragma unroll
      for (int ks=0; ks<3; ++ks){
        const int ab = rb1 + ks*32 + quad*8;
        Ba[ks] = *(const short8*)&a1[s][0][ab];
        Bb[ks] = *(const short8*)&a1[s][1][ab];
      }
#pragma unroll
      for (int tp=0; tp<2; ++tp){
        f32x4 C = bi1[tp];
#pragma unroll
        for (int ks=0; ks<3; ++ks){
          C = MFMA(A1w[tp][ks], Ba[ks], C);   // w_hi * a_hi
          C = MFMA(A1w[tp][ks], Bb[ks], C);   // w_hi * a_lo
          C = MFMA(A2w[tp][ks], Ba[ks], C);   // w_lo * a_hi
        }
        const float ig = sigf(C[0]), fg = sigf(C[1]);
        const float gg = fmaxf(C[2],0.f), og = sigf(C[3]);
        const float cn = fg*c1s[tp] + ig*gg; c1s[tp] = cn;
        const float h = og*fmaxf(cn,0.f);
        unsigned short s1,s2; split2(h,s1,s2);
        a1[ns][0][hw1+4*tp] = s1; a1[ns][1][hw1+4*tp] = s2;
      }
    }
    // ---- L2: z2(t-1) + gates -> h2(t-1) (all waves, 1 instance each) ----
    if (t >= 1){
      f32x4 C = bi2;
#pragma unroll
      for (int ks=0; ks<2; ++ks){
        const int ab = rb1 + 24 + ks*32 + quad*8;
        short8 Ba = *(const short8*)&a1[s][0][ab];
        short8 Bb = *(const short8*)&a1[s][1][ab];
        C = MFMA(A1w2[ks], Ba, C);
        C = MFMA(A1w2[ks], Bb, C);
        C = MFMA(A2w2[ks], Ba, C);
      }
      {
        const int ab = rb2 + quad*8;
        short8 Ba = *(const short8*)&a2[s][0][ab];
        short8 Bb = *(const short8*)&a2[s][1][ab];
        C = MFMA(A1w2[2], Ba, C);
        C = MFMA(A1w2[2], Bb, C);
        C = MFMA(A2w2[2], Ba, C);
      }
      const float ig = sigf(C[0]), fg = sigf(C[1]);
      const float gg = fmaxf(C[2],0.f), og = sigf(C[3]);
      const float cn = fg*c2s + ig*gg; c2s = cn;
      const float h = og*fmaxf(cn,0.f);
      if (t < TT){
        unsigned short s1,s2; split2(h,s1,s2);
        a2[ns][0][hw2] = s1; a2[ns][1][hw2] = s2;
      } else {
        h2ws[(size_t)(b0+arow)*32 + 4*w7 + quad] = h;   // final h2(TT-1)
      }
    }
    // ---- x staging: write x(t+1), prefetch x(t+3) ----
    if (st && t < TT-1){
      unsigned short s1,s2;
      split2(va,s1,s2); a1[ns][0][pr*AS1+pf]=s1; a1[ns][1][pr*AS1+pf]=s2;
      va = vb;
      if (t+3 < TT) vb = xp[(t+3)*FF];
    }
    __syncthreads();
  }
}

// ---------------- ae_C: L3 + fused dense -> out[B][T][24] ----------------
__global__ __launch_bounds__(1024,4) void ae_C(
    const float* __restrict__ h2ws,
    const float* __restrict__ W3, const float* __restrict__ U3, const float* __restrict__ b3,
    const float* __restrict__ Wd, const float* __restrict__ bd,
    float* __restrict__ out)
{
  constexpr int AS3 = 72, A2H = 40;
  __shared__ __align__(16) unsigned short a3[2][2][ROWS*AS3];  // [slot][split][row*AS3 + h3(64)|pad]
  __shared__ __align__(16) unsigned short a2h[2][ROWS*A2H];    // h2 splits (static)

  const int tid = threadIdx.x, wave = tid>>6, lane = tid&63;
  const int quad = lane>>4, li = lane&15;
  const int w7 = wave&7, rg = wave>>3;
  const int b0 = blockIdx.x*ROWS;
  const int arow = rg*16 + li;

  // U3 A-frags: tiles tl = 2*w7+tp
  short8 A1u[2][2], A2u[2][2];
  short8 A1w3[2], A2w3[2];
  f32x4 bi3[2];
#pragma unroll
  for (int tp=0; tp<2; ++tp){
    const int tl = 2*w7 + tp;
    const int zc = (li&3)*64 + 4*tl + (li>>2);
#pragma unroll
    for (int ks=0; ks<2; ++ks){
      short8 v1, v2;
#pragma unroll
      for (int j=0; j<8; ++j){
        const int k = ks*32 + quad*8 + j;
        float w = U3[k*256+zc];
        unsigned short s1,s2; split2(w,s1,s2);
        v1[j]=(short)s1; v2[j]=(short)s2;
      }
      A1u[tp][ks]=v1; A2u[tp][ks]=v2;
    }
    { // W3 (K=32, prologue only)
      short8 v1, v2;
#pragma unroll
      for (int j=0; j<8; ++j){
        const int k = quad*8 + j;
        float w = W3[k*256+zc];
        unsigned short s1,s2; split2(w,s1,s2);
        v1[j]=(short)s1; v2[j]=(short)s2;
      }
      A1w3[tp]=v1; A2w3[tp]=v2;
    }
#pragma unroll
    for (int i2=0;i2<4;++i2) bi3[tp][i2] = b3[i2*64 + 4*tl + quad];
  }

  // dense B-frags: waves with w7<2 (waves 0,1 for rg0; 8,9 for rg1)
  const bool dW = (w7 < 2);
  const int dcol = w7*16 + li;
  const bool dOK = dW && (dcol < 24);
  const float bdv = dOK ? bd[dcol] : 0.f;
  short8 Bd1[2], Bd2[2];
  if (dW){
#pragma unroll
    for (int ks=0; ks<2; ++ks){
      short8 v1, v2;
#pragma unroll
      for (int j=0; j<8; ++j){
        const int k = ks*32 + quad*8 + j;
        float w = dOK ? Wd[k*24+dcol] : 0.f;
        unsigned short s1,s2; split2(w,s1,s2);
        v1[j]=(short)s1; v2[j]=(short)s2;
      }
      Bd1[ks]=v1; Bd2[ks]=v2;
    }
  }

  // zero a3 (both slots: h3(-1)=0 and pads), stage h2 splits
  { unsigned* p = (unsigned*)a3; for (int i=tid;i<2*2*ROWS*AS3/2;i+=1024) p[i]=0u; }
  {
    const int r = tid>>5, ch = tid&31;
    unsigned short s1,s2; split2(h2ws[(size_t)(b0+r)*32 + ch], s1,s2);
    a2h[0][r*A2H+ch]=s1; a2h[1][r*A2H+ch]=s2;
  }
  __syncthreads();

  // ZR = b3 + h2@W3 (per-lane, C-init for every phase)
  f32x4 zr[2];
  {
    const int ab = arow*A2H + quad*8;
    short8 Ba = *(const short8*)&a2h[0][ab];
    short8 Bb = *(const short8*)&a2h[1][ab];
#pragma unroll
    for (int tp=0; tp<2; ++tp){
      f32x4 C = bi3[tp];
      C = MFMA(A1w3[tp], Ba, C);
      C = MFMA(A1w3[tp], Bb, C);
      C = MFMA(A2w3[tp], Ba, C);
      zr[tp] = C;
    }
  }
  float c3s[2] = {0.f,0.f};
  const int rb3 = arow*AS3;
  const int hw3 = rb3 + 8*w7 + quad;       // +4*tp

#pragma unroll 1
  for (int t=0; t<=TT; ++t){
    const int s = t&1, ns = s^1;
    if (t < TT){
      short8 Ba[2], Bb[2];
#pragma unroll
      for (int ks=0; ks<2; ++ks){
        const int ab = rb3 + ks*32 + quad*8;
        Ba[ks] = *(const short8*)&a3[s][0][ab];
        Bb[ks] = *(const short8*)&a3[s][1][ab];
      }
#pragma unroll
      for (int tp=0; tp<2; ++tp){
        f32x4 C = zr[tp];
#pragma unroll
        for (int ks=0; ks<2; ++ks){
          C = MFMA(A1u[tp][ks], Ba[ks], C);
          C = MFMA(A1u[tp][ks], Bb[ks], C);
          C = MFMA(A2u[tp][ks], Ba[ks], C);
        }
        const float ig = sigf(C[0]), fg = sigf(C[1]);
        const float gg = fmaxf(C[2],0.f), og = sigf(C[3]);
        const float cn = fg*c3s[tp] + ig*gg; c3s[tp] = cn;
        const float h = og*fmaxf(cn,0.f);
        unsigned short s1,s2; split2(h,s1,s2);
        a3[ns][0][hw3+4*tp]=s1; a3[ns][1][hw3+4*tp]=s2;
      }
      // dense on h3(t-1) (same B-frags), out column t-1
      if (dW && t > 0){
        f32x4 Cd = {bdv,bdv,bdv,bdv};
#pragma unroll
        for (int ks=0; ks<2; ++ks){
          Cd = MFMA(Ba[ks], Bd1[ks], Cd);   // a_hi * w_hi (normal orientation)
          Cd = MFMA(Ba[ks], Bd2[ks], Cd);   // a_hi * w_lo
          Cd = MFMA(Bb[ks], Bd1[ks], Cd);   // a_lo * w_hi
        }
        if (dcol < 24){
#pragma unroll
          for (int i2=0;i2<4;++i2)
            out[((size_t)(b0+rg*16+quad*4+i2)*TT + (t-1))*FF + dcol] = Cd[i2];
        }
      }
    } else {
      // t == TT: final dense on h3(TT-1)
      if (dW){
        f32x4 Cd = {bdv,bdv,bdv,bdv};
#pragma unroll
        for (int ks=0; ks<2; ++ks){
          const int ab = rb3 + ks*32 + quad*8;
          short8 Ba = *(const short8*)&a3[s][0][ab];
          short8 Bb = *(const short8*)&a3[s][1][ab];
          Cd = MFMA(Ba, Bd1[ks], Cd);
          Cd = MFMA(Ba, Bd2[ks], Cd);
          Cd = MFMA(Bb, Bd1[ks], Cd);
        }
        if (dcol < 24){
#pragma unroll
          for (int i2=0;i2<4;++i2)
            out[((size_t)(b0+rg*16+quad*4+i2)*TT + (TT-1))*FF + dcol] = Cd[i2];
        }
      }
    }
    __syncthreads();
  }
}

extern "C" void kernel_launch(void* const* d_in, const int* in_sizes, int n_in,
                              void* d_out, int out_size, void* d_ws, size_t ws_size,
                              hipStream_t stream){
  const float* x  = (const float*)d_in[0];
  const float* W1 = (const float*)d_in[1];
  const float* U1 = (const float*)d_in[2];
  const float* b1 = (const float*)d_in[3];
  const float* W2 = (const float*)d_in[4];
  const float* U2 = (const float*)d_in[5];
  const float* b2 = (const float*)d_in[6];
  const float* W3 = (const float*)d_in[7];
  const float* U3 = (const float*)d_in[8];
  const float* b3 = (const float*)d_in[9];
  const float* Wd = (const float*)d_in[10];
  const float* bd = (const float*)d_in[11];
  float* out = (float*)d_out;
  float* h2ws = (float*)d_ws;                  // [B][32] = 1 MB

  hipLaunchKernelGGL(ae_A, dim3(BB/ROWS), dim3(1024), 0, stream,
                     x, W1, U1, b1, W2, U2, b2, h2ws);
  hipLaunchKernelGGL(ae_C, dim3(BB/ROWS), dim3(1024), 0, stream,
                     h2ws, W3, U3, b3, Wd, bd, out);
}